// Round 13
// baseline (115.262 us; speedup 1.0000x reference)
//
#include <hip/hip_runtime.h>
#include <stdint.h>
#include <stddef.h>

typedef __attribute__((ext_vector_type(8))) short short8;
typedef __attribute__((ext_vector_type(4))) short short4v;
typedef __attribute__((ext_vector_type(4))) float f32x4;

typedef const __attribute__((address_space(3))) char* lds_cp;

#define GLDS16(gp, lp)                                                        \
    __builtin_amdgcn_global_load_lds(                                         \
        (const __attribute__((address_space(1))) void*)(gp),                  \
        (__attribute__((address_space(3))) void*)(lp), 16, 0, 0)

__device__ __forceinline__ short8 ldsr16(lds_cp p) {
    short8 v;
    asm volatile("ds_read_b128 %0, %1" : "=v"(v) : "v"(p));
    return v;
}

template <int N>
__device__ __forceinline__ void wait_lgkm() {
    if constexpr (N == 0) asm volatile("s_waitcnt lgkmcnt(0)" ::: "memory");
    else if constexpr (N == 2) asm volatile("s_waitcnt lgkmcnt(2)" ::: "memory");
    else if constexpr (N == 4) asm volatile("s_waitcnt lgkmcnt(4)" ::: "memory");
    else if constexpr (N == 8) asm volatile("s_waitcnt lgkmcnt(8)" ::: "memory");
    else static_assert(N == 0, "unsupported count");
    __builtin_amdgcn_sched_barrier(0);
}

template <int N>
__device__ __forceinline__ void wait_vm() {
    if constexpr (N == 0) asm volatile("s_waitcnt vmcnt(0)" ::: "memory");
    else if constexpr (N == 2) asm volatile("s_waitcnt vmcnt(2)" ::: "memory");
    else if constexpr (N == 4) asm volatile("s_waitcnt vmcnt(4)" ::: "memory");
    else if constexpr (N == 8) asm volatile("s_waitcnt vmcnt(8)" ::: "memory");
    else static_assert(N == 0, "unsupported count");
}

__device__ __forceinline__ unsigned short f2bf(float f) {
    union { float f; uint32_t u; } v;
    v.f = f;
    uint32_t u = v.u;
    u += 0x7FFFu + ((u >> 16) & 1u);
    return (unsigned short)(u >> 16);
}

// ---------------- prep: struct_pack (blocks 0..9599) + weight transpose (9600..10367) ----
__global__ __launch_bounds__(256) void prep(
    const float* __restrict__ feat0, const float* __restrict__ feat1,
    const float* __restrict__ pts0,  const float* __restrict__ pts1,
    const int* __restrict__ ids0,    const int* __restrict__ ids1,
    const float* __restrict__ W1,    const float* __restrict__ W2,
    unsigned short* __restrict__ xw,
    unsigned short* __restrict__ w1t, unsigned short* __restrict__ w2t)
{
    __shared__ float tile[32][33];
    int b = blockIdx.x;
    if (b < 9600) {
        const int m = b * 4 + (threadIdx.x >> 6);
        const int t = m / 19200;
        const int r = m % 19200;
        const int n = r / 4800;
        const int l = r % 4800;
        const float* feat = t ? feat1 : feat0;
        const float* pts  = (t ? pts1 : pts0) + (size_t)n * (307200 * 3);
        const int*   ids  = (t ? ids1 : ids0) + n * 128;
        const int a = threadIdx.x & 63;

        const int lr = l / 80, lc = l % 80;
        const int p  = (lr * 8) * 640 + lc * 8;
        const float cx = pts[p * 3 + 0], cy = pts[p * 3 + 1], cz = pts[p * 3 + 2];

        const int id0 = ids[a], id1 = ids[a + 64];
        const float d0x = cx - pts[id0 * 3 + 0];
        const float d0y = cy - pts[id0 * 3 + 1];
        const float d0z = cz - pts[id0 * 3 + 2];
        const float d0d = d0x * d0x + d0y * d0y + d0z * d0z;
        const float d1x = cx - pts[id1 * 3 + 0];
        const float d1y = cy - pts[id1 * 3 + 1];
        const float d1z = cz - pts[id1 * 3 + 2];
        const float d1d = d1x * d1x + d1y * d1y + d1z * d1z;

        float p0 = fabsf(d0x) + fabsf(d1x);
        float p1 = fabsf(d0y) + fabsf(d1y);
        float p2 = fabsf(d0z) + fabsf(d1z);
        float p3 = d0d + d1d;
#pragma unroll
        for (int off = 32; off; off >>= 1) {
            p0 += __shfl_xor(p0, off);
            p1 += __shfl_xor(p1, off);
            p2 += __shfl_xor(p2, off);
            p3 += __shfl_xor(p3, off);
        }
        const float i0 = 1.0f / p0, i1 = 1.0f / p1, i2 = 1.0f / p2, i3 = 1.0f / p3;

        unsigned short* xrow = xw + (size_t)m * 768;
        const float* frow = feat + (size_t)(n * 4800 + l) * 256;
        const float4 fv = ((const float4*)frow)[a];
        short4v s4;
        s4.x = (short)f2bf(fv.x); s4.y = (short)f2bf(fv.y);
        s4.z = (short)f2bf(fv.z); s4.w = (short)f2bf(fv.w);
        *(short4v*)(xrow + a * 4) = s4;

        xrow[256 + 0 * 128 + a]      = f2bf(d0x * i0);
        xrow[256 + 0 * 128 + a + 64] = f2bf(d1x * i0);
        xrow[256 + 1 * 128 + a]      = f2bf(d0y * i1);
        xrow[256 + 1 * 128 + a + 64] = f2bf(d1y * i1);
        xrow[256 + 2 * 128 + a]      = f2bf(d0z * i2);
        xrow[256 + 2 * 128 + a + 64] = f2bf(d1z * i2);
        xrow[256 + 3 * 128 + a]      = f2bf(d0d * i3);
        xrow[256 + 3 * 128 + a + 64] = f2bf(d1d * i3);
    } else {
        b -= 9600;
        const float* src; unsigned short* dst; int C, bx, by;
        if (b < 576) { src = W1; dst = w1t; C = 768; bx = b % 24; by = b / 24; }
        else { b -= 576; src = W2; dst = w2t; C = 256; bx = b % 8; by = b / 8; }
        const int R = 768;
        const int c0 = bx * 32, r0 = by * 32;
        const int tx = threadIdx.x & 31, ty0 = threadIdx.x >> 5;
#pragma unroll
        for (int rr = 0; rr < 4; ++rr) {
            const int ty = ty0 * 4 + rr;
            tile[ty][tx] = src[(size_t)(r0 + ty) * C + (c0 + tx)];
        }
        __syncthreads();
#pragma unroll
        for (int rr = 0; rr < 4; ++rr) {
            const int ty = ty0 * 4 + rr;
            dst[(size_t)(c0 + ty) * R + (r0 + tx)] = f2bf(tile[tx][ty]);
        }
    }
}

// ---------------- GEMM1: m201-style 8-phase schedule (gemm8) ----------------
// h = relu(x @ W1t^T + b1). BM=BN=256, BK=64. 8 waves 2M x 4N (wave tile 128x64).
// LDS 128KB: A[parity][ks-half][256x32] + B[parity][ks-half][256x32], 16KB regions.
// Per K-tile: 4 phases = (ks, nj-pair) quadrants; each phase:
//   {ds_reads (10 or 2), stage ONE half-tile (2 gloads), barrier, lgkm(0)+sched_barrier,
//    setprio(1), 16 MFMA, setprio(0), [vmcnt(8) at P2/P4], barrier}.
// Stage placement (race-free, barrier-sealed): P1: hA1(t+1), P2: hB1(t+1),
// P3: hA0(t+2), P4: hB0(t+2). ks-half regions die exactly 2 phases before re-stage.
// vmcnt(8)=4 half-tiles in flight (in-order retirement guarantees older reads);
// drain-0 only in the last two tiles. Swizzle (64B rows): chunk ^= (row>>1)&3,
// inverse on the global source (r7: 0 conflicts).
__global__ __launch_bounds__(512, 2) void gemm8(
    const unsigned short* __restrict__ A,
    const unsigned short* __restrict__ Bt,
    const float* __restrict__ bias,
    unsigned short* __restrict__ Cout,
    int K, int N, int ntx, int q8, int r8)
{
    extern __shared__ char lds[];
    char* ldsB = lds + 65536;
    const int nt = K >> 6;

    const int bid = blockIdx.x;
    const int xcd = bid & 7, idx = bid >> 3;
    const int w = (xcd < r8 ? xcd * (q8 + 1) : r8 * (q8 + 1) + (xcd - r8) * q8) + idx;
    const int n0 = (w % ntx) * 256;
    const int m0 = (w / ntx) * 256;

    const int tid = threadIdx.x;
    const int lane = tid & 63;
    const int wv = tid >> 6;
    const int wr = wv >> 2;        // 0..1 (M, 128-row groups)
    const int wc = wv & 3;         // 0..3 (N, 64-col groups)

    // ---- staging: per gload, 64 lanes x16B = 16 rows x 64B. Pre-swizzled source chunk.
    const int srow = lane >> 2;                       // 0..15
    const int scl  = (lane & 3) ^ ((lane >> 3) & 3);  // logical chunk (inverse swizzle)
    const unsigned short* gAs = A  + (size_t)(m0 + wv * 32 + srow) * K + scl * 8;
    const unsigned short* gBs = Bt + (size_t)(n0 + wv * 32 + srow) * K + scl * 8;
    char* ldsAw = lds  + (wv * 32) * 64;
    char* ldsBw = ldsB + (wv * 32) * 64;

    // stage half h (32 k-cols) of tile with k-offset kt into parity p
    auto stA = [&](int p, int h, int kt) {
        GLDS16(gAs + kt + h * 32,                 ldsAw + p * 32768 + h * 16384);
        GLDS16(gAs + (size_t)16 * K + kt + h * 32, ldsAw + p * 32768 + h * 16384 + 1024);
    };
    auto stB = [&](int p, int h, int kt) {
        GLDS16(gBs + kt + h * 32,                 ldsBw + p * 32768 + h * 16384);
        GLDS16(gBs + (size_t)16 * K + kt + h * 32, ldsBw + p * 32768 + h * 16384 + 1024);
    };

    // ---- fragment reads (64B rows): chunk = kbh ^ ((rsel>>1)&3) -> 2-way (free)
    const int rsel = lane & 15;
    const int kbh  = lane >> 4;
    const int ck   = (kbh ^ ((rsel >> 1) & 3)) * 16;
    const int aOff = (wr * 128 + rsel) * 64 + ck;
    const int bOff = (wc * 64 + rsel) * 64 + ck;

    auto LDA = [&](int p, int ks, int mi) -> short8 {
        return ldsr16((lds_cp)(lds + p * 32768 + ks * 16384 + aOff + mi * 1024));
    };
    auto LDB = [&](int p, int ks, int nj) -> short8 {
        return ldsr16((lds_cp)(ldsB + p * 32768 + ks * 16384 + bOff + nj * 1024));
    };

    f32x4 acc[8][4] = {};
    short8 aF[8], bFa, bFb;

    // ---- prologue: hA0(0),hB0(0),hA1(0),hB1(0),hA0(1),hB0(1); vmcnt(8)+barrier
    stA(0, 0, 0); stB(0, 0, 0);
    stA(0, 1, 0); stB(0, 1, 0);
    if (nt > 1) { stA(1, 0, 64); stB(1, 0, 64); }
    wait_vm<8>();
    __builtin_amdgcn_s_barrier();

    for (int t = 0; t < nt; ++t) {
        const int p = t & 1, q = p ^ 1;
        const int kt1 = (t + 1) << 6;
        const int kt2 = (t + 2) << 6;
        const bool s1 = (t + 1) < nt;
        const bool s2 = (t + 2) < nt;

        // ---- P1: reads A(ks0) x8 + B(ks0) nj0,1; stage hA1(t+1); MFMA mi x nj{0,1} ks0
#pragma unroll
        for (int mi = 0; mi < 8; ++mi) aF[mi] = LDA(p, 0, mi);
        bFa = LDB(p, 0, 0); bFb = LDB(p, 0, 1);
        if (s1) stA(q, 1, kt1);
        __builtin_amdgcn_s_barrier();
        wait_lgkm<0>();
        __builtin_amdgcn_s_setprio(1);
#pragma unroll
        for (int mi = 0; mi < 8; ++mi) {
            acc[mi][0] = __builtin_amdgcn_mfma_f32_16x16x32_bf16(aF[mi], bFa, acc[mi][0], 0, 0, 0);
            acc[mi][1] = __builtin_amdgcn_mfma_f32_16x16x32_bf16(aF[mi], bFb, acc[mi][1], 0, 0, 0);
        }
        __builtin_amdgcn_s_setprio(0);
        __builtin_amdgcn_s_barrier();

        // ---- P2: reads B(ks0) nj2,3; stage hB1(t+1); MFMA mi x nj{2,3} ks0; vmcnt
        bFa = LDB(p, 0, 2); bFb = LDB(p, 0, 3);
        if (s1) stB(q, 1, kt1);
        __builtin_amdgcn_s_barrier();
        wait_lgkm<0>();
        __builtin_amdgcn_s_setprio(1);
#pragma unroll
        for (int mi = 0; mi < 8; ++mi) {
            acc[mi][2] = __builtin_amdgcn_mfma_f32_16x16x32_bf16(aF[mi], bFa, acc[mi][2], 0, 0, 0);
            acc[mi][3] = __builtin_amdgcn_mfma_f32_16x16x32_bf16(aF[mi], bFb, acc[mi][3], 0, 0, 0);
        }
        __builtin_amdgcn_s_setprio(0);
        if (t < nt - 1) wait_vm<8>();
        else            wait_vm<0>();
        __builtin_amdgcn_s_barrier();

        // ---- P3: reads A(ks1) x8 + B(ks1) nj0,1; stage hA0(t+2); MFMA mi x nj{0,1} ks1
#pragma unroll
        for (int mi = 0; mi < 8; ++mi) aF[mi] = LDA(p, 1, mi);
        bFa = LDB(p, 1, 0); bFb = LDB(p, 1, 1);
        if (s2) stA(p, 0, kt2);
        __builtin_amdgcn_s_barrier();
        wait_lgkm<0>();
        __builtin_amdgcn_s_setprio(1);
#pragma unroll
        for (int mi = 0; mi < 8; ++mi) {
            acc[mi][0] = __builtin_amdgcn_mfma_f32_16x16x32_bf16(aF[mi], bFa, acc[mi][0], 0, 0, 0);
            acc[mi][1] = __builtin_amdgcn_mfma_f32_16x16x32_bf16(aF[mi], bFb, acc[mi][1], 0, 0, 0);
        }
        __builtin_amdgcn_s_setprio(0);
        __builtin_amdgcn_s_barrier();

        // ---- P4: reads B(ks1) nj2,3; stage hB0(t+2); MFMA mi x nj{2,3} ks1; vmcnt+barrier
        bFa = LDB(p, 1, 2); bFb = LDB(p, 1, 3);
        if (s2) stB(p, 0, kt2);
        __builtin_amdgcn_s_barrier();
        wait_lgkm<0>();
        __builtin_amdgcn_s_setprio(1);
#pragma unroll
        for (int mi = 0; mi < 8; ++mi) {
            acc[mi][2] = __builtin_amdgcn_mfma_f32_16x16x32_bf16(aF[mi], bFa, acc[mi][2], 0, 0, 0);
            acc[mi][3] = __builtin_amdgcn_mfma_f32_16x16x32_bf16(aF[mi], bFb, acc[mi][3], 0, 0, 0);
        }
        __builtin_amdgcn_s_setprio(0);
        if (s1) {
            if (s2) wait_vm<8>();
            else    wait_vm<0>();
            __builtin_amdgcn_s_barrier();
        }
    }

    // ---- epilogue (r12, verified): LDS-staged coalesced bf16 stores
    const int crow = (lane >> 4) * 4;
    const int ccol = lane & 15;
    __syncthreads();
    unsigned short* cl = (unsigned short*)lds;
#pragma unroll
    for (int nj = 0; nj < 4; ++nj) {
        const int col = wc * 64 + nj * 16 + ccol;
        const float bv = bias[n0 + col];
        const int c = col >> 3;
#pragma unroll
        for (int mi = 0; mi < 8; ++mi) {
#pragma unroll
            for (int rg = 0; rg < 4; ++rg) {
                const int row = wr * 128 + mi * 16 + crow + rg;
                float v = fmaxf(acc[mi][nj][rg] + bv, 0.0f);
                const int pc = (c & ~7) | ((c ^ row) & 7);
                cl[row * 256 + pc * 8 + (col & 7)] = f2bf(v);
            }
        }
    }
    __syncthreads();
#pragma unroll
    for (int h2 = 0; h2 < 2; ++h2) {
        const int rrow = wv * 32 + h2 * 16 + (lane >> 2);
        unsigned short* outp = Cout + (size_t)(m0 + rrow) * N + n0;
#pragma unroll
        for (int s = 0; s < 8; ++s) {
            const int c = s * 4 + (lane & 3);
            const int pc = (c & ~7) | ((c ^ rrow) & 7);
            short8 vv = *(const short8*)&cl[rrow * 256 + pc * 8];
            *(short8*)(outp + c * 8) = vv;
        }
    }
}

// ---------------- GEMM2: r9/r12 barrier-free gemm_t (unchanged, known-good) ----------
template <int MI, int NJ, int WRN_LOG, bool RELU, bool OUT_BF16>
__global__ __launch_bounds__(512, 2) void gemm_t(
    const unsigned short* __restrict__ A,
    const unsigned short* __restrict__ Bt,
    const float* __restrict__ bias,
    void* __restrict__ Cout,
    int K, int N, int ntx, int q8, int r8)
{
    constexpr int WRN = 1 << WRN_LOG;
    constexpr int WRM = 8 / WRN;
    constexpr int BM = WRM * MI * 16;
    constexpr int BN = WRN * NJ * 16;
    constexpr int ASLOT = BM * 128;
    constexpr int BSLOT = BN * 128;
    constexpr int ALD = BM / 64;
    constexpr int BLD = BN / 64;

    extern __shared__ char lds[];
    char* ldsB = lds + 3 * ASLOT;
    const int nt = K >> 6;

    const int bid = blockIdx.x;
    const int xcd = bid & 7, idx = bid >> 3;
    const int w = (xcd < r8 ? xcd * (q8 + 1) : r8 * (q8 + 1) + (xcd - r8) * q8) + idx;
    const int n0 = (w % ntx) * BN;
    const int m0 = (w / ntx) * BM;

    const int tid = threadIdx.x;
    const int lane = tid & 63;
    const int wv = tid >> 6;
    const int wr = wv >> WRN_LOG;
    const int wc = wv & (WRN - 1);

    const int slr = lane >> 3;
    const int kc  = (lane & 7) ^ slr;
    const unsigned short* gA = A  + (size_t)(m0 + wv * 8 + slr) * K + kc * 8;
    const unsigned short* gB = Bt + (size_t)(n0 + wv * 8 + slr) * K + kc * 8;

    auto stA = [&](int slot, int i, int kt) {
        GLDS16(gA + (size_t)i * 64 * K + kt, lds + slot * ASLOT + (i * 64 + wv * 8) * 128);
    };
    auto stB = [&](int slot, int j, int kt) {
        GLDS16(gB + (size_t)j * 64 * K + kt, ldsB + slot * BSLOT + (j * 64 + wv * 8) * 128);
    };

    const int rsel = lane & 15;
    const int kbh  = lane >> 4;
    const int ck0 = ((kbh) ^ (rsel & 7)) * 16;
    const int ck1 = ((4 + kbh) ^ (rsel & 7)) * 16;
    const int aRowB = (wr * (MI * 16) + rsel) * 128;
    const int bRowB = (wc * (NJ * 16) + rsel) * 128;

    auto LDA = [&](int slot, int mi, int ks) -> short8 {
        return ldsr16((lds_cp)(lds + slot * ASLOT + aRowB + mi * 2048 + (ks ? ck1 : ck0)));
    };
    auto LDB = [&](int slot, int nj, int ks) -> short8 {
        return ldsr16((lds_cp)(ldsB + slot * BSLOT + bRowB + nj * 2048 + (ks ? ck1 : ck0)));
    };

    f32x4 acc[MI][NJ] = {};
    short8 aL[MI / 2], aH[MI / 2], aL1[MI / 2], aH1[MI / 2], bF0[NJ], bF1[NJ];

    {
#pragma unroll
        for (int i = 0; i < ALD; ++i) stA(0, i, 0);
#pragma unroll
        for (int j = 0; j < BLD; ++j) stB(0, j, 0);
        if (nt > 1) {
#pragma unroll
            for (int i = 0; i < ALD; ++i) stA(1, i, 64);
            wait_vm<ALD>();
        } else {
            wait_vm<0>();
        }
        __builtin_amdgcn_s_barrier();
    }

    int cb3 = 0;
    for (int t = 0; t < nt; ++t) {
        const int cb2 = t & 1;
        const int sb2 = cb2 ^ 1;
        int sa3 = cb3 + 2; if (sa3 >= 3) sa3 -= 3;
        const int kt1 = (t + 1) << 6;
        const int kt2 = (t + 2) << 6;
        const bool stb = (t + 1) < nt;
        const bool sta = (t + 2) < nt;

#pragma unroll
        for (int nj = 0; nj < NJ; ++nj) bF0[nj] = LDB(cb2, nj, 0);
#pragma unroll
        for (int mi = 0; mi < MI / 2; ++mi) aL[mi] = LDA(cb3, mi, 0);
#pragma unroll
        for (int mi = 0; mi < MI / 2; ++mi) aH[mi] = LDA(cb3, MI / 2 + mi, 0);

        wait_lgkm<MI / 2>();
        __builtin_amdgcn_s_setprio(1);
#pragma unroll
        for (int mi = 0; mi < MI / 2; ++mi)
#pragma unroll
            for (int nj = 0; nj < NJ; ++nj)
                acc[mi][nj] = __builtin_amdgcn_mfma_f32_16x16x32_bf16(aL[mi], bF0[nj], acc[mi][nj], 0, 0, 0);
        __builtin_amdgcn_s_setprio(0);

#pragma unroll
        for (int nj = 0; nj < NJ; ++nj) bF1[nj] = LDB(cb2, nj, 1);
        if (stb) {
#pragma unroll
            for (int j = 0; j < BLD; ++j) stB(sb2, j, kt1);
        }

        wait_lgkm<NJ>();
        __builtin_amdgcn_s_setprio(1);
#pragma unroll
        for (int mi = 0; mi < MI / 2; ++mi)
#pragma unroll
            for (int nj = 0; nj < NJ; ++nj)
                acc[MI / 2 + mi][nj] = __builtin_amdgcn_mfma_f32_16x16x32_bf16(aH[mi], bF0[nj], acc[MI / 2 + mi][nj], 0, 0, 0);
        __builtin_amdgcn_s_setprio(0);

#pragma unroll
        for (int mi = 0; mi < MI / 2; ++mi) aL1[mi] = LDA(cb3, mi, 1);
#pragma unroll
        for (int mi = 0; mi < MI / 2; ++mi) aH1[mi] = LDA(cb3, MI / 2 + mi, 1);
        if (sta) {
#pragma unroll
            for (int i = 0; i < ALD; ++i) stA(sa3, i, kt2);
        }

        wait_lgkm<MI / 2>();
        __builtin_amdgcn_s_setprio(1);
#pragma unroll
        for (int mi = 0; mi < MI / 2; ++mi)
#pragma unroll
            for (int nj = 0; nj < NJ; ++nj)
                acc[mi][nj] = __builtin_amdgcn_mfma_f32_16x16x32_bf16(aL1[mi], bF1[nj], acc[mi][nj], 0, 0, 0);
        __builtin_amdgcn_s_setprio(0);

        wait_lgkm<0>();
        __builtin_amdgcn_s_setprio(1);
#pragma unroll
        for (int mi = 0; mi < MI / 2; ++mi)
#pragma unroll
            for (int nj = 0; nj < NJ; ++nj)
                acc[MI / 2 + mi][nj] = __builtin_amdgcn_mfma_f32_16x16x32_bf16(aH1[mi], bF1[nj], acc[MI / 2 + mi][nj], 0, 0, 0);
        __builtin_amdgcn_s_setprio(0);

        if (t + 1 < nt) {
            if (sta) wait_vm<ALD>();
            else     wait_vm<0>();
            __builtin_amdgcn_s_barrier();
        }
        cb3 = (cb3 + 1 == 3) ? 0 : cb3 + 1;
    }

    const int crow = (lane >> 4) * 4;
    const int ccol = lane & 15;
#pragma unroll
    for (int nj = 0; nj < NJ; ++nj) {
        const int col = n0 + wc * (NJ * 16) + nj * 16 + ccol;
        const float bv = bias[col];
#pragma unroll
        for (int mi = 0; mi < MI; ++mi) {
#pragma unroll
            for (int rg = 0; rg < 4; ++rg) {
                const int row = m0 + wr * (MI * 16) + mi * 16 + crow + rg;
                float v = acc[mi][nj][rg] + bv;
                if (RELU) v = fmaxf(v, 0.0f);
                if (OUT_BF16) {
                    ((unsigned short*)Cout)[(size_t)row * N + col] = f2bf(v);
                } else {
                    ((float*)Cout)[(size_t)row * N + col] = v;
                }
            }
        }
    }
}

extern "C" void kernel_launch(void* const* d_in, const int* in_sizes, int n_in,
                              void* d_out, int out_size, void* d_ws, size_t ws_size,
                              hipStream_t stream) {
    const float* feat0 = (const float*)d_in[0];
    const float* feat1 = (const float*)d_in[1];
    const float* pts0  = (const float*)d_in[2];
    const float* pts1  = (const float*)d_in[3];
    const int*   ids0  = (const int*)d_in[4];
    const int*   ids1  = (const int*)d_in[5];
    const float* W1    = (const float*)d_in[6];
    const float* b1    = (const float*)d_in[7];
    const float* W2    = (const float*)d_in[8];
    const float* b2    = (const float*)d_in[9];
    float* out = (float*)d_out;

    char* ws = (char*)d_ws;
    unsigned short* xw  = (unsigned short*)(ws);
    unsigned short* h   = (unsigned short*)(ws + 58982400);
    unsigned short* w1t = (unsigned short*)(ws + 117964800);
    unsigned short* w2t = (unsigned short*)(ws + 119144448);

    // GEMM1 (gemm8): LDS = 128 KB (rings; reused for 128KB C-tile in epilogue)
    const int LDS1 = 131072;
    // GEMM2 (gemm_t<4,2,2>): 3*16K + 2*16K = 80 KB, 2 blk/CU
    const int LDS2 = 3 * 16384 + 2 * 16384;
    (void)hipFuncSetAttribute((const void*)&gemm8,
                              hipFuncAttributeMaxDynamicSharedMemorySize, LDS1);
    (void)hipFuncSetAttribute((const void*)&gemm_t<4, 2, 2, false, false>,
                              hipFuncAttributeMaxDynamicSharedMemorySize, LDS2);

    // prep: struct_pack (9600 blocks) + both weight transposes (768 blocks)
    prep<<<10368, 256, 0, stream>>>(feat0, feat1, pts0, pts1, ids0, ids1,
                                    W1, W2, xw, w1t, w2t);

    // GEMM1: h = relu(x @ W1 + b1)  M=38400, N=768 -> tiles 150m x 3n = 450 wg (q=56, r=2)
    gemm8<<<450, 512, LDS1, stream>>>(xw, w1t, b1, h, 768, 768, 3, 56, 2);
    // GEMM2: out = h @ W2 + b2      M=38400, N=256 -> tiles 300m x 2n = 600 wg (q=75, r=0)
    gemm_t<4, 2, 2, false, false><<<600, 512, LDS2, stream>>>(h, w2t, b2, (void*)out, 768, 256, 2, 75, 0);
}

// Round 14
// 105.221 us; speedup vs baseline: 1.0954x; 1.0954x over previous
//
#include <hip/hip_runtime.h>
#include <stdint.h>
#include <stddef.h>

typedef __attribute__((ext_vector_type(8))) short short8;
typedef __attribute__((ext_vector_type(4))) short short4v;
typedef __attribute__((ext_vector_type(4))) float f32x4;

typedef const __attribute__((address_space(3))) char* lds_cp;

#define GLDS16(gp, lp)                                                        \
    __builtin_amdgcn_global_load_lds(                                         \
        (const __attribute__((address_space(1))) void*)(gp),                  \
        (__attribute__((address_space(3))) void*)(lp), 16, 0, 0)

// Opaque LDS read: no compiler-inserted waits; completion via counted lgkmcnt.
__device__ __forceinline__ short8 ldsr16(lds_cp p) {
    short8 v;
    asm volatile("ds_read_b128 %0, %1" : "=v"(v) : "v"(p));
    return v;
}

// rule #18: counted lgkm wait + sched_barrier(0) so MFMA can't hoist above it
template <int N>
__device__ __forceinline__ void wait_lgkm() {
    if constexpr (N == 0) asm volatile("s_waitcnt lgkmcnt(0)" ::: "memory");
    else if constexpr (N == 2) asm volatile("s_waitcnt lgkmcnt(2)" ::: "memory");
    else if constexpr (N == 4) asm volatile("s_waitcnt lgkmcnt(4)" ::: "memory");
    else if constexpr (N == 8) asm volatile("s_waitcnt lgkmcnt(8)" ::: "memory");
    else static_assert(N == 0, "unsupported count");
    __builtin_amdgcn_sched_barrier(0);
}

template <int N>
__device__ __forceinline__ void wait_vm() {
    if constexpr (N == 0) asm volatile("s_waitcnt vmcnt(0)" ::: "memory");
    else if constexpr (N == 2) asm volatile("s_waitcnt vmcnt(2)" ::: "memory");
    else if constexpr (N == 4) asm volatile("s_waitcnt vmcnt(4)" ::: "memory");
    else static_assert(N == 0, "unsupported count");
}

__device__ __forceinline__ unsigned short f2bf(float f) {
    union { float f; uint32_t u; } v;
    v.f = f;
    uint32_t u = v.u;
    u += 0x7FFFu + ((u >> 16) & 1u);
    return (unsigned short)(u >> 16);
}

// ---------------- prep: struct_pack (blocks 0..9599) + weight transpose (9600..10367) ----
__global__ __launch_bounds__(256) void prep(
    const float* __restrict__ feat0, const float* __restrict__ feat1,
    const float* __restrict__ pts0,  const float* __restrict__ pts1,
    const int* __restrict__ ids0,    const int* __restrict__ ids1,
    const float* __restrict__ W1,    const float* __restrict__ W2,
    unsigned short* __restrict__ xw,
    unsigned short* __restrict__ w1t, unsigned short* __restrict__ w2t)
{
    __shared__ float tile[32][33];
    int b = blockIdx.x;
    if (b < 9600) {
        const int m = b * 4 + (threadIdx.x >> 6);
        const int t = m / 19200;
        const int r = m % 19200;
        const int n = r / 4800;
        const int l = r % 4800;
        const float* feat = t ? feat1 : feat0;
        const float* pts  = (t ? pts1 : pts0) + (size_t)n * (307200 * 3);
        const int*   ids  = (t ? ids1 : ids0) + n * 128;
        const int a = threadIdx.x & 63;

        const int lr = l / 80, lc = l % 80;
        const int p  = (lr * 8) * 640 + lc * 8;
        const float cx = pts[p * 3 + 0], cy = pts[p * 3 + 1], cz = pts[p * 3 + 2];

        const int id0 = ids[a], id1 = ids[a + 64];
        const float d0x = cx - pts[id0 * 3 + 0];
        const float d0y = cy - pts[id0 * 3 + 1];
        const float d0z = cz - pts[id0 * 3 + 2];
        const float d0d = d0x * d0x + d0y * d0y + d0z * d0z;
        const float d1x = cx - pts[id1 * 3 + 0];
        const float d1y = cy - pts[id1 * 3 + 1];
        const float d1z = cz - pts[id1 * 3 + 2];
        const float d1d = d1x * d1x + d1y * d1y + d1z * d1z;

        float p0 = fabsf(d0x) + fabsf(d1x);
        float p1 = fabsf(d0y) + fabsf(d1y);
        float p2 = fabsf(d0z) + fabsf(d1z);
        float p3 = d0d + d1d;
#pragma unroll
        for (int off = 32; off; off >>= 1) {
            p0 += __shfl_xor(p0, off);
            p1 += __shfl_xor(p1, off);
            p2 += __shfl_xor(p2, off);
            p3 += __shfl_xor(p3, off);
        }
        const float i0 = 1.0f / p0, i1 = 1.0f / p1, i2 = 1.0f / p2, i3 = 1.0f / p3;

        unsigned short* xrow = xw + (size_t)m * 768;
        const float* frow = feat + (size_t)(n * 4800 + l) * 256;
        const float4 fv = ((const float4*)frow)[a];
        short4v s4;
        s4.x = (short)f2bf(fv.x); s4.y = (short)f2bf(fv.y);
        s4.z = (short)f2bf(fv.z); s4.w = (short)f2bf(fv.w);
        *(short4v*)(xrow + a * 4) = s4;

        xrow[256 + 0 * 128 + a]      = f2bf(d0x * i0);
        xrow[256 + 0 * 128 + a + 64] = f2bf(d1x * i0);
        xrow[256 + 1 * 128 + a]      = f2bf(d0y * i1);
        xrow[256 + 1 * 128 + a + 64] = f2bf(d1y * i1);
        xrow[256 + 2 * 128 + a]      = f2bf(d0z * i2);
        xrow[256 + 2 * 128 + a + 64] = f2bf(d1z * i2);
        xrow[256 + 3 * 128 + a]      = f2bf(d0d * i3);
        xrow[256 + 3 * 128 + a + 64] = f2bf(d1d * i3);
    } else {
        b -= 9600;
        const float* src; unsigned short* dst; int C, bx, by;
        if (b < 576) { src = W1; dst = w1t; C = 768; bx = b % 24; by = b / 24; }
        else { b -= 576; src = W2; dst = w2t; C = 256; bx = b % 8; by = b / 8; }
        const int R = 768;
        const int c0 = bx * 32, r0 = by * 32;
        const int tx = threadIdx.x & 31, ty0 = threadIdx.x >> 5;
#pragma unroll
        for (int rr = 0; rr < 4; ++rr) {
            const int ty = ty0 * 4 + rr;
            tile[ty][tx] = src[(size_t)(r0 + ty) * C + (c0 + tx)];
        }
        __syncthreads();
#pragma unroll
        for (int rr = 0; rr < 4; ++rr) {
            const int ty = ty0 * 4 + rr;
            dst[(size_t)(c0 + ty) * R + (r0 + tx)] = f2bf(tile[tx][ty]);
        }
    }
}

// ---------------- 8-wave barrier-free-intra-tile MFMA GEMM (r6/r9/r12 structure) ----
// C = act(A @ Bt^T + bias). A:[M,K] bf16, Bt:[N,K] bf16 (pre-transposed weight).
// BM = WRM*MI*16, BN = WRN*NJ*16, BK = 64. LDS: A ring-3 (stage t+2) + B ring-2 (stage t+1).
// No intra-tile barriers: ds_reads in groups, consumed via counted lgkmcnt.
// Boundary per tile: s_waitcnt vmcnt(ALD) + s_barrier. Zero-conflict XOR swizzle.
// OUT_BF16 epilogue stages C in LDS (16B-chunk XOR swizzle) and streams full
// 64B-line short8 stores (kills the 1.75x HBM write amplification of scalar stores).
template <int MI, int NJ, int WRN_LOG, bool RELU, bool OUT_BF16>
__global__ __launch_bounds__(512, 2) void gemm_t(
    const unsigned short* __restrict__ A,
    const unsigned short* __restrict__ Bt,
    const float* __restrict__ bias,
    void* __restrict__ Cout,
    int K, int N, int ntx, int q8, int r8)
{
    constexpr int WRN = 1 << WRN_LOG;
    constexpr int WRM = 8 / WRN;
    constexpr int BM = WRM * MI * 16;
    constexpr int BN = WRN * NJ * 16;
    constexpr int ASLOT = BM * 128;
    constexpr int BSLOT = BN * 128;
    constexpr int ALD = BM / 64;
    constexpr int BLD = BN / 64;

    extern __shared__ char lds[];
    char* ldsB = lds + 3 * ASLOT;
    const int nt = K >> 6;

    const int bid = blockIdx.x;
    const int xcd = bid & 7, idx = bid >> 3;
    const int w = (xcd < r8 ? xcd * (q8 + 1) : r8 * (q8 + 1) + (xcd - r8) * q8) + idx;
    const int n0 = (w % ntx) * BN;
    const int m0 = (w / ntx) * BM;

    const int tid = threadIdx.x;
    const int lane = tid & 63;
    const int wv = tid >> 6;
    const int wr = wv >> WRN_LOG;
    const int wc = wv & (WRN - 1);

    // staging (pre-swizzled global source, linear LDS dest)
    const int slr = lane >> 3;
    const int kc  = (lane & 7) ^ slr;
    const unsigned short* gA = A  + (size_t)(m0 + wv * 8 + slr) * K + kc * 8;
    const unsigned short* gB = Bt + (size_t)(n0 + wv * 8 + slr) * K + kc * 8;

    auto stA = [&](int slot, int i, int kt) {
        GLDS16(gA + (size_t)i * 64 * K + kt, lds + slot * ASLOT + (i * 64 + wv * 8) * 128);
    };
    auto stB = [&](int slot, int j, int kt) {
        GLDS16(gB + (size_t)j * 64 * K + kt, ldsB + slot * BSLOT + (j * 64 + wv * 8) * 128);
    };

    // read-side addressing (zero-conflict swizzle)
    const int rsel = lane & 15;
    const int kbh  = lane >> 4;
    const int ck0 = ((kbh) ^ (rsel & 7)) * 16;
    const int ck1 = ((4 + kbh) ^ (rsel & 7)) * 16;
    const int aRowB = (wr * (MI * 16) + rsel) * 128;
    const int bRowB = (wc * (NJ * 16) + rsel) * 128;

    auto LDA = [&](int slot, int mi, int ks) -> short8 {
        return ldsr16((lds_cp)(lds + slot * ASLOT + aRowB + mi * 2048 + (ks ? ck1 : ck0)));
    };
    auto LDB = [&](int slot, int nj, int ks) -> short8 {
        return ldsr16((lds_cp)(ldsB + slot * BSLOT + bRowB + nj * 2048 + (ks ? ck1 : ck0)));
    };

    f32x4 acc[MI][NJ] = {};
    short8 aL[MI / 2], aH[MI / 2], aL1[MI / 2], aH1[MI / 2], bF0[NJ], bF1[NJ];

    // ---- prologue: A(0), B(0), A(1); keep A(1) in flight
    {
#pragma unroll
        for (int i = 0; i < ALD; ++i) stA(0, i, 0);
#pragma unroll
        for (int j = 0; j < BLD; ++j) stB(0, j, 0);
        if (nt > 1) {
#pragma unroll
            for (int i = 0; i < ALD; ++i) stA(1, i, 64);
            wait_vm<ALD>();
        } else {
            wait_vm<0>();
        }
        __builtin_amdgcn_s_barrier();
    }

    int cb3 = 0;  // t % 3
    for (int t = 0; t < nt; ++t) {
        const int cb2 = t & 1;
        const int sb2 = cb2 ^ 1;
        int sa3 = cb3 + 2; if (sa3 >= 3) sa3 -= 3;
        const int kt1 = (t + 1) << 6;
        const int kt2 = (t + 2) << 6;
        const bool stb = (t + 1) < nt;
        const bool sta = (t + 2) < nt;

        // ---- G1: B(ks0) + A-lo(ks0); G2: A-hi(ks0)
#pragma unroll
        for (int nj = 0; nj < NJ; ++nj) bF0[nj] = LDB(cb2, nj, 0);
#pragma unroll
        for (int mi = 0; mi < MI / 2; ++mi) aL[mi] = LDA(cb3, mi, 0);
#pragma unroll
        for (int mi = 0; mi < MI / 2; ++mi) aH[mi] = LDA(cb3, MI / 2 + mi, 0);

        // ---- c1: lo x all (ks0) once G1 landed
        wait_lgkm<MI / 2>();
        __builtin_amdgcn_s_setprio(1);
#pragma unroll
        for (int mi = 0; mi < MI / 2; ++mi)
#pragma unroll
            for (int nj = 0; nj < NJ; ++nj)
                acc[mi][nj] = __builtin_amdgcn_mfma_f32_16x16x32_bf16(aL[mi], bF0[nj], acc[mi][nj], 0, 0, 0);
        __builtin_amdgcn_s_setprio(0);

        // ---- G3: B(ks1); stage B(t+1)
#pragma unroll
        for (int nj = 0; nj < NJ; ++nj) bF1[nj] = LDB(cb2, nj, 1);
        if (stb) {
#pragma unroll
            for (int j = 0; j < BLD; ++j) stB(sb2, j, kt1);
        }

        // ---- c2: hi x all (ks0) once G2 landed
        wait_lgkm<NJ>();
        __builtin_amdgcn_s_setprio(1);
#pragma unroll
        for (int mi = 0; mi < MI / 2; ++mi)
#pragma unroll
            for (int nj = 0; nj < NJ; ++nj)
                acc[MI / 2 + mi][nj] = __builtin_amdgcn_mfma_f32_16x16x32_bf16(aH[mi], bF0[nj], acc[MI / 2 + mi][nj], 0, 0, 0);
        __builtin_amdgcn_s_setprio(0);

        // ---- G4: A-lo(ks1) + A-hi(ks1); stage A(t+2)
#pragma unroll
        for (int mi = 0; mi < MI / 2; ++mi) aL1[mi] = LDA(cb3, mi, 1);
#pragma unroll
        for (int mi = 0; mi < MI / 2; ++mi) aH1[mi] = LDA(cb3, MI / 2 + mi, 1);
        if (sta) {
#pragma unroll
            for (int i = 0; i < ALD; ++i) stA(sa3, i, kt2);
        }

        // ---- c3: lo x all (ks1)
        wait_lgkm<MI / 2>();
        __builtin_amdgcn_s_setprio(1);
#pragma unroll
        for (int mi = 0; mi < MI / 2; ++mi)
#pragma unroll
            for (int nj = 0; nj < NJ; ++nj)
                acc[mi][nj] = __builtin_amdgcn_mfma_f32_16x16x32_bf16(aL1[mi], bF1[nj], acc[mi][nj], 0, 0, 0);
        __builtin_amdgcn_s_setprio(0);

        // ---- c4: hi x all (ks1)
        wait_lgkm<0>();
        __builtin_amdgcn_s_setprio(1);
#pragma unroll
        for (int mi = 0; mi < MI / 2; ++mi)
#pragma unroll
            for (int nj = 0; nj < NJ; ++nj)
                acc[MI / 2 + mi][nj] = __builtin_amdgcn_mfma_f32_16x16x32_bf16(aH1[mi], bF1[nj], acc[MI / 2 + mi][nj], 0, 0, 0);
        __builtin_amdgcn_s_setprio(0);

        // ---- tile boundary
        if (t + 1 < nt) {
            if (sta) wait_vm<ALD>();
            else     wait_vm<0>();
            __builtin_amdgcn_s_barrier();
        }
        cb3 = (cb3 + 1 == 3) ? 0 : cb3 + 1;
    }

    const int crow = (lane >> 4) * 4;
    const int ccol = lane & 15;

    if constexpr (OUT_BF16 && BM == 256) {
        // ---- LDS-staged coalesced epilogue (bf16): [BM rows][BN cols], 16B-chunk swizzle
        __syncthreads();   // every wave passed its wait_lgkm<0> -> no outstanding LDS reads
        unsigned short* cl = (unsigned short*)lds;
#pragma unroll
        for (int nj = 0; nj < NJ; ++nj) {
            const int col = wc * (NJ * 16) + nj * 16 + ccol;
            const float bv = bias[n0 + col];
            const int c = col >> 3;
#pragma unroll
            for (int mi = 0; mi < MI; ++mi) {
#pragma unroll
                for (int rg = 0; rg < 4; ++rg) {
                    const int row = wr * (MI * 16) + mi * 16 + crow + rg;
                    float v = acc[mi][nj][rg] + bv;
                    if (RELU) v = fmaxf(v, 0.0f);
                    const int pc = (c & ~7) | ((c ^ row) & 7);
                    cl[row * BN + pc * 8 + (col & 7)] = f2bf(v);
                }
            }
        }
        __syncthreads();
        // read back: wave owns 32 rows (two 16-row halves); 4 lanes = one 64B line
#pragma unroll
        for (int h2 = 0; h2 < 2; ++h2) {
            const int rrow = wv * 32 + h2 * 16 + (lane >> 2);
            unsigned short* outp = (unsigned short*)Cout + (size_t)(m0 + rrow) * N + n0;
#pragma unroll
            for (int s = 0; s < BN / 32; ++s) {
                const int c = s * 4 + (lane & 3);
                const int pc = (c & ~7) | ((c ^ rrow) & 7);
                short8 vv = *(const short8*)&cl[rrow * BN + pc * 8];
                *(short8*)(outp + c * 8) = vv;
            }
        }
    } else {
        // ---- scalar epilogue
#pragma unroll
        for (int nj = 0; nj < NJ; ++nj) {
            const int col = n0 + wc * (NJ * 16) + nj * 16 + ccol;
            const float bv = bias[col];
#pragma unroll
            for (int mi = 0; mi < MI; ++mi) {
#pragma unroll
                for (int rg = 0; rg < 4; ++rg) {
                    const int row = m0 + wr * (MI * 16) + mi * 16 + crow + rg;
                    float v = acc[mi][nj][rg] + bv;
                    if (RELU) v = fmaxf(v, 0.0f);
                    if (OUT_BF16) {
                        ((unsigned short*)Cout)[(size_t)row * N + col] = f2bf(v);
                    } else {
                        ((float*)Cout)[(size_t)row * N + col] = v;
                    }
                }
            }
        }
    }
}

extern "C" void kernel_launch(void* const* d_in, const int* in_sizes, int n_in,
                              void* d_out, int out_size, void* d_ws, size_t ws_size,
                              hipStream_t stream) {
    const float* feat0 = (const float*)d_in[0];
    const float* feat1 = (const float*)d_in[1];
    const float* pts0  = (const float*)d_in[2];
    const float* pts1  = (const float*)d_in[3];
    const int*   ids0  = (const int*)d_in[4];
    const int*   ids1  = (const int*)d_in[5];
    const float* W1    = (const float*)d_in[6];
    const float* b1    = (const float*)d_in[7];
    const float* W2    = (const float*)d_in[8];
    const float* b2    = (const float*)d_in[9];
    float* out = (float*)d_out;

    char* ws = (char*)d_ws;
    unsigned short* xw  = (unsigned short*)(ws);
    unsigned short* h   = (unsigned short*)(ws + 58982400);
    unsigned short* w1t = (unsigned short*)(ws + 117964800);
    unsigned short* w2t = (unsigned short*)(ws + 119144448);

    // GEMM1: <8,4,2> 256x256 tile, wave 128x64; LDS = 160 KB (also holds 128KB C-tile)
    const int LDS1 = 3 * 32768 + 2 * 32768;
    // GEMM2: <4,2,2> 128x128 tile, wave 64x32; LDS = 80 KB, 2 blk/CU
    const int LDS2 = 3 * 16384 + 2 * 16384;
    (void)hipFuncSetAttribute((const void*)&gemm_t<8, 4, 2, true, true>,
                              hipFuncAttributeMaxDynamicSharedMemorySize, LDS1);
    (void)hipFuncSetAttribute((const void*)&gemm_t<4, 2, 2, false, false>,
                              hipFuncAttributeMaxDynamicSharedMemorySize, LDS2);

    // prep: struct_pack (9600 blocks) + both weight transposes (768 blocks)
    prep<<<10368, 256, 0, stream>>>(feat0, feat1, pts0, pts1, ids0, ids1,
                                    W1, W2, xw, w1t, w2t);

    // GEMM1: h = relu(x @ W1 + b1)  M=38400, N=768 -> tiles 150m x 3n = 450 wg (q=56, r=2)
    gemm_t<8, 4, 2, true, true><<<450, 512, LDS1, stream>>>(xw, w1t, b1, (void*)h, 768, 768, 3, 56, 2);
    // GEMM2: out = h @ W2 + b2      M=38400, N=256 -> tiles 300m x 2n = 600 wg (q=75, r=0)
    gemm_t<4, 2, 2, false, false><<<600, 512, LDS2, stream>>>(h, w2t, b2, (void*)out, 768, 256, 2, 75, 0);
}